// Round 1
// baseline (667.310 us; speedup 1.0000x reference)
//
#include <hip/hip_runtime.h>
#include <hip/hip_bf16.h>

#define CC 64
#define NN 9216
#define NB 2

typedef __attribute__((ext_vector_type(4))) float f32x4;
typedef __attribute__((ext_vector_type(8))) short bf16x8;

static __device__ __forceinline__ short f2bf(float f) {
    union { float f; unsigned u; } a; a.f = f;
    unsigned r = a.u + 0x7FFFu + ((a.u >> 16) & 1u);
    return (short)(r >> 16);
}

// ---------------------------------------------------------------------------
// Kernel 1: fused Q/K/V 1x1-conv projections.
//   x  [B][C][N] f32  ->  Q [B][N][C] bf16 (theta), K [B][N][C] bf16 (phi),
//                         V [B][C][N] bf16 (g, natural conv layout)
// ---------------------------------------------------------------------------
__global__ __launch_bounds__(256) void proj_kernel(
    const float* __restrict__ x,
    const float* __restrict__ gw, const float* __restrict__ gb,
    const float* __restrict__ tw, const float* __restrict__ tb,
    const float* __restrict__ pw, const float* __restrict__ pb,
    short* __restrict__ Qw, short* __restrict__ Kw, short* __restrict__ Vw)
{
    __shared__ float xs[64][68];          // [c][n] tile, pad 68 keeps reads 2-way
    __shared__ float wsm[3][64][64];      // g, theta, phi weights
    __shared__ float bsm[3][64];
    const int b  = blockIdx.x / (NN / 64);
    const int n0 = (blockIdx.x % (NN / 64)) * 64;
    const int t  = threadIdx.x;

    float* wf = &wsm[0][0][0];
    for (int i = t; i < 4096; i += 256) {
        wf[i]        = gw[i];
        wf[4096 + i] = tw[i];
        wf[8192 + i] = pw[i];
    }
    if (t < 64) { bsm[0][t] = gb[t]; bsm[1][t] = tb[t]; bsm[2][t] = pb[t]; }

    {   // stage x tile: 64 channels x 64 spatial
        const int c = t >> 2, q = t & 3;
        const float* src = x + ((size_t)b * CC + c) * NN + n0 + q * 16;
        #pragma unroll
        for (int i = 0; i < 4; ++i) {
            float4 v = ((const float4*)src)[i];
            xs[c][q * 16 + i * 4 + 0] = v.x;
            xs[c][q * 16 + i * 4 + 1] = v.y;
            xs[c][q * 16 + i * 4 + 2] = v.z;
            xs[c][q * 16 + i * 4 + 3] = v.w;
        }
    }
    __syncthreads();

    const int n = t & 63, og = t >> 6;     // this thread: spatial n, o-group
    float xr[64];
    #pragma unroll
    for (int c = 0; c < 64; ++c) xr[c] = xs[c][n];   // column in registers

    const size_t qkbase = ((size_t)b * NN + n0 + n) * CC;
    for (int oi = 0; oi < 16; ++oi) {
        const int o = og * 16 + oi;
        float a0 = bsm[0][o], a1 = bsm[1][o], a2 = bsm[2][o];
        #pragma unroll
        for (int c = 0; c < 64; ++c) {
            const float xv = xr[c];
            a0 += wsm[0][o][c] * xv;   // g
            a1 += wsm[1][o][c] * xv;   // theta
            a2 += wsm[2][o][c] * xv;   // phi
        }
        Vw[((size_t)b * CC + o) * NN + n0 + n] = f2bf(a0);
        Qw[qkbase + o] = f2bf(a1);
        Kw[qkbase + o] = f2bf(a2);
    }
}

// ---------------------------------------------------------------------------
// Kernel 2: flash attention. 2 waves/block, 16 q-rows/wave, KV tile = 64.
//   S = Q K^T (no scale), online softmax, Y = P V.  Y [B][N][C] f32.
// ---------------------------------------------------------------------------
__global__ __launch_bounds__(128) void attn_kernel(
    const short* __restrict__ Qw, const short* __restrict__ Kw,
    const short* __restrict__ Vw, float* __restrict__ Yw)
{
    __shared__ short kl[64][72];      // K tile [j][c], pad 72 (row stride 144B)
    __shared__ short vl[64][72];      // V tile [c][j]
    __shared__ short pl[2][16][72];   // per-wave P tile [i][j]
    const int b  = blockIdx.x / (NN / 32);
    const int q0 = (blockIdx.x % (NN / 32)) * 32;
    const int t  = threadIdx.x;
    const int w  = t >> 6, l = t & 63;
    const int lg = l >> 4, lr = l & 15;

    // Q fragments live in registers for the whole kernel.
    const short* qp = Qw + ((size_t)b * NN + q0 + w * 16 + lr) * CC + lg * 8;
    const bf16x8 qf0 = *(const bf16x8*)qp;
    const bf16x8 qf1 = *(const bf16x8*)(qp + 32);

    f32x4 yacc[4];
    #pragma unroll
    for (int u = 0; u < 4; ++u) yacc[u] = (f32x4){0.f, 0.f, 0.f, 0.f};
    float m[4]  = {-1e30f, -1e30f, -1e30f, -1e30f};
    float se[4] = {0.f, 0.f, 0.f, 0.f};

    const short* Kb = Kw + (size_t)b * NN * CC;
    const short* Vb = Vw + (size_t)b * CC * NN;

    for (int kt = 0; kt < NN / 64; ++kt) {
        __syncthreads();
        // cooperative stage: K rows [j][c] and V rows [c][j], 8KB each
        #pragma unroll
        for (int r = 0; r < 4; ++r) {
            const int idx = t + r * 128;
            const int row = idx >> 3, c8 = (idx & 7) * 8;
            *(bf16x8*)&kl[row][c8] = *(const bf16x8*)(Kb + ((size_t)kt * 64 + row) * CC + c8);
            *(bf16x8*)&vl[row][c8] = *(const bf16x8*)(Vb + (size_t)row * NN + kt * 64 + c8);
        }
        __syncthreads();

        // S = Q K^T : 4 column-tiles of 16, K split k=0..31 / 32..63
        f32x4 s[4];
        #pragma unroll
        for (int tt = 0; tt < 4; ++tt) {
            f32x4 acc = (f32x4){0.f, 0.f, 0.f, 0.f};
            const bf16x8 k0 = *(const bf16x8*)&kl[tt * 16 + lr][lg * 8];
            acc = __builtin_amdgcn_mfma_f32_16x16x32_bf16(qf0, k0, acc, 0, 0, 0);
            const bf16x8 k1 = *(const bf16x8*)&kl[tt * 16 + lr][32 + lg * 8];
            acc = __builtin_amdgcn_mfma_f32_16x16x32_bf16(qf1, k1, acc, 0, 0, 0);
            s[tt] = acc;
        }

        // online softmax. reg r holds row (lg*4 + r); row lives in 16 lanes.
        #pragma unroll
        for (int r = 0; r < 4; ++r) {
            float mx = fmaxf(fmaxf(s[0][r], s[1][r]), fmaxf(s[2][r], s[3][r]));
            mx = fmaxf(mx, __shfl_xor(mx, 1));
            mx = fmaxf(mx, __shfl_xor(mx, 2));
            mx = fmaxf(mx, __shfl_xor(mx, 4));
            mx = fmaxf(mx, __shfl_xor(mx, 8));
            const float mnew = fmaxf(m[r], mx);
            const float sc = __expf(m[r] - mnew);
            float rs = 0.f;
            #pragma unroll
            for (int tt = 0; tt < 4; ++tt) {
                const float p = __expf(s[tt][r] - mnew);
                rs += p;
                pl[w][lg * 4 + r][lr + tt * 16] = f2bf(p);
            }
            rs += __shfl_xor(rs, 1);
            rs += __shfl_xor(rs, 2);
            rs += __shfl_xor(rs, 4);
            rs += __shfl_xor(rs, 8);
            se[r] = se[r] * sc + rs;
            m[r] = mnew;
            #pragma unroll
            for (int u = 0; u < 4; ++u) yacc[u][r] *= sc;
        }

        // Y += P V : P is A-operand (rows i), V[c][j] LDS is B-operand
        #pragma unroll
        for (int kk = 0; kk < 2; ++kk) {
            const bf16x8 pf = *(const bf16x8*)&pl[w][lr][kk * 32 + lg * 8];
            #pragma unroll
            for (int u = 0; u < 4; ++u) {
                const bf16x8 vf = *(const bf16x8*)&vl[u * 16 + lr][kk * 32 + lg * 8];
                yacc[u] = __builtin_amdgcn_mfma_f32_16x16x32_bf16(pf, vf, yacc[u], 0, 0, 0);
            }
        }
    }

    float inv[4];
    #pragma unroll
    for (int r = 0; r < 4; ++r) inv[r] = 1.f / se[r];
    float* yp = Yw + ((size_t)b * NN + q0 + w * 16) * CC;
    #pragma unroll
    for (int u = 0; u < 4; ++u) {
        #pragma unroll
        for (int r = 0; r < 4; ++r)
            yp[(size_t)(lg * 4 + r) * CC + u * 16 + lr] = yacc[u][r] * inv[r];
    }
}

// ---------------------------------------------------------------------------
// Kernel 3: W 1x1 conv + BatchNorm (folded affine) + residual.
//   Y [B][N][C] f32 -> out [B][C][N] f32
// ---------------------------------------------------------------------------
__global__ __launch_bounds__(256) void out_kernel(
    const float* __restrict__ Yw, const float* __restrict__ x,
    const float* __restrict__ ww, const float* __restrict__ wb,
    const float* __restrict__ gam, const float* __restrict__ bet,
    const float* __restrict__ mu, const float* __restrict__ var,
    float* __restrict__ out)
{
    __shared__ float ys[64][65];
    __shared__ float wsm[64][64];
    __shared__ float scl[64], shf[64];
    const int b  = blockIdx.x / (NN / 64);
    const int n0 = (blockIdx.x % (NN / 64)) * 64;
    const int t  = threadIdx.x;

    float* wf = &wsm[0][0];
    for (int i = t; i < 4096; i += 256) wf[i] = ww[i];
    if (t < 64) {
        const float s = gam[t] * rsqrtf(var[t] + 1e-5f);
        scl[t] = s;
        shf[t] = bet[t] + (wb[t] - mu[t]) * s;   // fold conv bias + BN shift
    }
    {   // stage y tile [n][c]
        const int n = t >> 2, q = t & 3;
        const float* src = Yw + ((size_t)b * NN + n0 + n) * CC + q * 16;
        #pragma unroll
        for (int i = 0; i < 4; ++i) {
            float4 v = ((const float4*)src)[i];
            ys[n][q * 16 + i * 4 + 0] = v.x;
            ys[n][q * 16 + i * 4 + 1] = v.y;
            ys[n][q * 16 + i * 4 + 2] = v.z;
            ys[n][q * 16 + i * 4 + 3] = v.w;
        }
    }
    __syncthreads();

    const int n = t & 63, og = t >> 6;
    float yr[64];
    #pragma unroll
    for (int c = 0; c < 64; ++c) yr[c] = ys[n][c];

    for (int oi = 0; oi < 16; ++oi) {
        const int o = og * 16 + oi;
        float acc = 0.f;
        #pragma unroll
        for (int c = 0; c < 64; ++c) acc += wsm[o][c] * yr[c];
        const size_t oidx = ((size_t)b * CC + o) * NN + n0 + n;
        out[oidx] = acc * scl[o] + shf[o] + x[oidx];
    }
}

// ---------------------------------------------------------------------------
extern "C" void kernel_launch(void* const* d_in, const int* in_sizes, int n_in,
                              void* d_out, int out_size, void* d_ws, size_t ws_size,
                              hipStream_t stream) {
    const float* x    = (const float*)d_in[0];
    const float* g_w  = (const float*)d_in[1];
    const float* g_b  = (const float*)d_in[2];
    const float* th_w = (const float*)d_in[3];
    const float* th_b = (const float*)d_in[4];
    const float* ph_w = (const float*)d_in[5];
    const float* ph_b = (const float*)d_in[6];
    const float* w_w  = (const float*)d_in[7];
    const float* w_b  = (const float*)d_in[8];
    const float* bn_g = (const float*)d_in[9];
    const float* bn_b = (const float*)d_in[10];
    const float* bn_m = (const float*)d_in[11];
    const float* bn_v = (const float*)d_in[12];
    float* out = (float*)d_out;

    // workspace layout (bytes): Q bf16 | K bf16 | V bf16 | Y f32  = ~11.3 MB
    char* wsp = (char*)d_ws;
    short* Qw = (short*)(wsp + 0);
    short* Kw = (short*)(wsp + 2359296);
    short* Vw = (short*)(wsp + 4718592);
    float* Yw = (float*)(wsp + 7077888);

    proj_kernel<<<NB * (NN / 64), 256, 0, stream>>>(x, g_w, g_b, th_w, th_b,
                                                    ph_w, ph_b, Qw, Kw, Vw);
    attn_kernel<<<NB * (NN / 32), 128, 0, stream>>>(Qw, Kw, Vw, Yw);
    out_kernel<<<NB * (NN / 64), 256, 0, stream>>>(Yw, x, w_w, w_b,
                                                   bn_g, bn_b, bn_m, bn_v, out);
}

// Round 2
// 360.344 us; speedup vs baseline: 1.8519x; 1.8519x over previous
//
#include <hip/hip_runtime.h>
#include <hip/hip_bf16.h>

#define CC 64
#define NN 9216
#define NB 2
#define NQT 288            // NN/32 q-tiles per batch
#define NKT 144            // NN/64 kv tiles

typedef __attribute__((ext_vector_type(4))) float f32x4;
typedef __attribute__((ext_vector_type(8))) short bf16x8;
typedef __attribute__((ext_vector_type(4))) unsigned int u32x4;

static __device__ __forceinline__ short f2bf(float f) {
    union { float f; unsigned u; } a; a.f = f;
    unsigned r = a.u + 0x7FFFu + ((a.u >> 16) & 1u);
    return (short)(r >> 16);
}

// ---------------------------------------------------------------------------
// Kernel 1: fused Q/K/V 1x1-conv projections. Weights via scalar loads
// (wave-uniform o forced with readfirstlane) -> s_load + v_fmac only.
//   x [B][C][N] f32 -> Q [B][N][C] bf16, K [B][N][C] bf16, V [B][C][N] bf16
// ---------------------------------------------------------------------------
__global__ __launch_bounds__(256) void proj_kernel(
    const float* __restrict__ x,
    const float* __restrict__ gw, const float* __restrict__ gb,
    const float* __restrict__ tw, const float* __restrict__ tb,
    const float* __restrict__ pw, const float* __restrict__ pb,
    short* __restrict__ Qw, short* __restrict__ Kw, short* __restrict__ Vw)
{
    __shared__ float xs[64][68];
    const int b  = blockIdx.x / (NN / 64);
    const int n0 = (blockIdx.x % (NN / 64)) * 64;
    const int t  = threadIdx.x;

    {   // stage x tile: 64 channels x 64 spatial
        const int c = t >> 2, q = t & 3;
        const float* src = x + ((size_t)b * CC + c) * NN + n0 + q * 16;
        #pragma unroll
        for (int i = 0; i < 4; ++i) {
            float4 v = ((const float4*)src)[i];
            xs[c][q * 16 + i * 4 + 0] = v.x;
            xs[c][q * 16 + i * 4 + 1] = v.y;
            xs[c][q * 16 + i * 4 + 2] = v.z;
            xs[c][q * 16 + i * 4 + 3] = v.w;
        }
    }
    __syncthreads();

    const int n  = t & 63;
    const int og = __builtin_amdgcn_readfirstlane(t >> 6);  // wave-uniform
    float xr[64];
    #pragma unroll
    for (int c = 0; c < 64; ++c) xr[c] = xs[c][n];

    bf16x8 qv0, qv1, kv0, kv1;
    #pragma unroll
    for (int oi = 0; oi < 16; ++oi) {
        const int o = og * 16 + oi;
        float a0 = gb[o], a1 = tb[o], a2 = pb[o];
        #pragma unroll
        for (int c = 0; c < 64; ++c) {
            const float xv = xr[c];
            a0 += gw[o * 64 + c] * xv;
            a1 += tw[o * 64 + c] * xv;
            a2 += pw[o * 64 + c] * xv;
        }
        Vw[((size_t)b * CC + o) * NN + n0 + n] = f2bf(a0);
        if (oi < 8) { qv0[oi] = f2bf(a1); kv0[oi] = f2bf(a2); }
        else        { qv1[oi - 8] = f2bf(a1); kv1[oi - 8] = f2bf(a2); }
    }
    const size_t qkbase = ((size_t)b * NN + n0 + n) * CC + og * 16;
    *(bf16x8*)&Qw[qkbase]     = qv0;
    *(bf16x8*)&Qw[qkbase + 8] = qv1;
    *(bf16x8*)&Kw[qkbase]     = kv0;
    *(bf16x8*)&Kw[qkbase + 8] = kv1;
}

// ---------------------------------------------------------------------------
// Kernel 2: flash attention, barrier-free / LDS-free.
//   One wave owns 32 q-rows; KV-split SP chunks of NKT/SP tiles.
//   Swapped QK^T: S^T = mfma(K, Q) -> lane holds j=tt*16+lg*4+r for i=lr.
//   P packed to bf16 in-register, shuffled into PV B-fragments.
//   Partials: Yp [SP][B][N][C] f32 (unnormalized), Mp/Sp [SP][B][N].
// ---------------------------------------------------------------------------
template<int SP>
__global__ __launch_bounds__(256) void attn_kernel(
    const short* __restrict__ Qw, const short* __restrict__ Kw,
    const short* __restrict__ Vw, float* __restrict__ Yp,
    float* __restrict__ Mp, float* __restrict__ Sp)
{
    constexpr int KCH = NKT / SP;
    const int gw  = blockIdx.x * 4 + (threadIdx.x >> 6);
    const int l   = threadIdx.x & 63;
    const int lr  = l & 15, lg = l >> 4;
    const int qt  = gw % NQT;
    const int rem = gw / NQT;
    const int b   = rem & 1;
    const int s   = rem >> 1;
    const int q0  = qt * 32;

    const short* Qb = Qw + (size_t)b * NN * CC;
    const short* Kb = Kw + (size_t)b * NN * CC;
    const short* Vb = Vw + (size_t)b * CC * NN;

    bf16x8 qf[2][2];
    #pragma unroll
    for (int qg = 0; qg < 2; ++qg)
        #pragma unroll
        for (int ch = 0; ch < 2; ++ch)
            qf[qg][ch] = *(const bf16x8*)(Qb + (size_t)(q0 + qg * 16 + lr) * CC + ch * 32 + lg * 8);

    f32x4 yacc[2][4];
    #pragma unroll
    for (int qg = 0; qg < 2; ++qg)
        #pragma unroll
        for (int u = 0; u < 4; ++u) yacc[qg][u] = (f32x4){0.f, 0.f, 0.f, 0.f};
    float m[2]  = {-1e30f, -1e30f};
    float se[2] = {0.f, 0.f};

    for (int kt = s * KCH; kt < s * KCH + KCH; ++kt) {
        const int jb = kt * 64;
        bf16x8 kf[4][2], vf[4][2];
        #pragma unroll
        for (int tt = 0; tt < 4; ++tt)
            #pragma unroll
            for (int ch = 0; ch < 2; ++ch)
                kf[tt][ch] = *(const bf16x8*)(Kb + (size_t)(jb + tt * 16 + lr) * CC + ch * 32 + lg * 8);
        #pragma unroll
        for (int u = 0; u < 4; ++u)
            #pragma unroll
            for (int jg = 0; jg < 2; ++jg)
                vf[u][jg] = *(const bf16x8*)(Vb + (size_t)(u * 16 + lr) * NN + jb + jg * 32 + lg * 8);

        #pragma unroll
        for (int qg = 0; qg < 2; ++qg) {
            // S^T tiles: lane holds S[j = jb+tt*16+lg*4+r][i = q0+qg*16+lr]
            f32x4 sv[4];
            #pragma unroll
            for (int tt = 0; tt < 4; ++tt) {
                f32x4 a = (f32x4){0.f, 0.f, 0.f, 0.f};
                a = __builtin_amdgcn_mfma_f32_16x16x32_bf16(kf[tt][0], qf[qg][0], a, 0, 0, 0);
                a = __builtin_amdgcn_mfma_f32_16x16x32_bf16(kf[tt][1], qf[qg][1], a, 0, 0, 0);
                sv[tt] = a;
            }
            // online softmax (row i = lr lives in 4 lanes: xor 16, 32)
            float mx = -1e30f;
            #pragma unroll
            for (int tt = 0; tt < 4; ++tt)
                #pragma unroll
                for (int r = 0; r < 4; ++r) mx = fmaxf(mx, sv[tt][r]);
            mx = fmaxf(mx, __shfl_xor(mx, 16));
            mx = fmaxf(mx, __shfl_xor(mx, 32));
            const float mnew = fmaxf(m[qg], mx);
            const float scal = __expf(m[qg] - mnew);
            float rs = 0.f;
            unsigned p2[4][2];     // quad Jq = tt*4+lg as 2 packed bf16 pairs
            #pragma unroll
            for (int tt = 0; tt < 4; ++tt) {
                const float pa = __expf(sv[tt][0] - mnew);
                const float pb2 = __expf(sv[tt][1] - mnew);
                const float pc = __expf(sv[tt][2] - mnew);
                const float pd = __expf(sv[tt][3] - mnew);
                rs += (pa + pb2) + (pc + pd);
                p2[tt][0] = (unsigned)(unsigned short)f2bf(pa) | ((unsigned)(unsigned short)f2bf(pb2) << 16);
                p2[tt][1] = (unsigned)(unsigned short)f2bf(pc) | ((unsigned)(unsigned short)f2bf(pd) << 16);
            }
            rs += __shfl_xor(rs, 16);
            rs += __shfl_xor(rs, 32);
            se[qg] = se[qg] * scal + rs;
            m[qg]  = mnew;
            #pragma unroll
            for (int u = 0; u < 4; ++u) yacc[qg][u] *= scal;   // lane-uniform

            // PV: build B-fragment (P^T) by shuffle, A = V from global
            #pragma unroll
            for (int jg = 0; jg < 2; ++jg) {
                unsigned bfr[4];
                #pragma unroll
                for (int q = 0; q < 4; ++q) {
                    const int qh = q >> 1, h = q & 1;
                    const int src = lr | ((((lg << 1) + qh) & 3) << 4);
                    const int c0 = __shfl((int)p2[jg * 2 + 0][h], src);
                    const int c1 = __shfl((int)p2[jg * 2 + 1][h], src);
                    bfr[q] = (unsigned)((lg & 2) ? c1 : c0);
                }
                u32x4 bt = {bfr[0], bfr[1], bfr[2], bfr[3]};
                const bf16x8 pbf = __builtin_bit_cast(bf16x8, bt);
                #pragma unroll
                for (int u = 0; u < 4; ++u)
                    yacc[qg][u] = __builtin_amdgcn_mfma_f32_16x16x32_bf16(vf[u][jg], pbf, yacc[qg][u], 0, 0, 0);
            }
        }
    }

    // write partials: yacc holds Y^T[c = u*16+lg*4+r][i = lr] (unnormalized)
    const size_t pbase = (size_t)(s * NB + b) * NN;
    #pragma unroll
    for (int qg = 0; qg < 2; ++qg) {
        const int n = q0 + qg * 16 + lr;
        float* yrow = Yp + (pbase + n) * CC;
        #pragma unroll
        for (int u = 0; u < 4; ++u)
            *(f32x4*)&yrow[u * 16 + lg * 4] = yacc[qg][u];
        if (lg == 0) { Mp[pbase + n] = m[qg]; Sp[pbase + n] = se[qg]; }
    }
}

// ---------------------------------------------------------------------------
// Kernel 3: merge KV-split partials + W conv (scalar weights) + BN + residual.
// ---------------------------------------------------------------------------
template<int SP>
__global__ __launch_bounds__(256) void out_kernel(
    const float* __restrict__ Yp, const float* __restrict__ Mp,
    const float* __restrict__ Sp, const float* __restrict__ x,
    const float* __restrict__ ww, const float* __restrict__ wb,
    const float* __restrict__ gam, const float* __restrict__ bet,
    const float* __restrict__ mu, const float* __restrict__ var,
    float* __restrict__ out)
{
    __shared__ float ys[64][65];
    __shared__ float wgt[SP][64];
    __shared__ float scl[64], shf[64];
    const int b  = blockIdx.x / (NN / 64);
    const int n0 = (blockIdx.x % (NN / 64)) * 64;
    const int t  = threadIdx.x;

    if (t < 64) {
        float e[SP], ssv[SP];
        float M = -1e30f;
        #pragma unroll
        for (int s = 0; s < SP; ++s) {
            e[s]   = Mp[(size_t)(s * NB + b) * NN + n0 + t];
            ssv[s] = Sp[(size_t)(s * NB + b) * NN + n0 + t];
            M = fmaxf(M, e[s]);
        }
        float den = 0.f;
        #pragma unroll
        for (int s = 0; s < SP; ++s) { e[s] = __expf(e[s] - M); den += e[s] * ssv[s]; }
        const float inv = 1.f / den;
        #pragma unroll
        for (int s = 0; s < SP; ++s) wgt[s][t] = e[s] * inv;
    } else if (t < 128) {
        const int c = t - 64;
        const float sc = gam[c] * rsqrtf(var[c] + 1e-5f);
        scl[c] = sc;
        shf[c] = bet[c] + (wb[c] - mu[c]) * sc;
    }
    __syncthreads();

    {   // merge-stage y tile [n][c]
        const int n = t >> 2, q = t & 3;
        float acc[16];
        #pragma unroll
        for (int i = 0; i < 16; ++i) acc[i] = 0.f;
        #pragma unroll
        for (int s = 0; s < SP; ++s) {
            const float w = wgt[s][n];
            const float* src = Yp + ((size_t)(s * NB + b) * NN + n0 + n) * CC + q * 16;
            #pragma unroll
            for (int i = 0; i < 4; ++i) {
                const float4 v = ((const float4*)src)[i];
                acc[i * 4 + 0] += w * v.x;
                acc[i * 4 + 1] += w * v.y;
                acc[i * 4 + 2] += w * v.z;
                acc[i * 4 + 3] += w * v.w;
            }
        }
        #pragma unroll
        for (int i = 0; i < 16; ++i) ys[n][q * 16 + i] = acc[i];
    }
    __syncthreads();

    const int n  = t & 63;
    const int og = __builtin_amdgcn_readfirstlane(t >> 6);
    float yr[64];
    #pragma unroll
    for (int c = 0; c < 64; ++c) yr[c] = ys[n][c];

    #pragma unroll
    for (int oi = 0; oi < 16; ++oi) {
        const int o = og * 16 + oi;
        float a0 = 0.f, a1 = 0.f;
        #pragma unroll
        for (int c = 0; c < 64; c += 2) {
            a0 += ww[o * 64 + c]     * yr[c];
            a1 += ww[o * 64 + c + 1] * yr[c + 1];
        }
        const size_t oidx = ((size_t)b * CC + o) * NN + n0 + n;
        out[oidx] = (a0 + a1) * scl[o] + shf[o] + x[oidx];
    }
}

// ---------------------------------------------------------------------------
extern "C" void kernel_launch(void* const* d_in, const int* in_sizes, int n_in,
                              void* d_out, int out_size, void* d_ws, size_t ws_size,
                              hipStream_t stream) {
    const float* x    = (const float*)d_in[0];
    const float* g_w  = (const float*)d_in[1];
    const float* g_b  = (const float*)d_in[2];
    const float* th_w = (const float*)d_in[3];
    const float* th_b = (const float*)d_in[4];
    const float* ph_w = (const float*)d_in[5];
    const float* ph_b = (const float*)d_in[6];
    const float* w_w  = (const float*)d_in[7];
    const float* w_b  = (const float*)d_in[8];
    const float* bn_g = (const float*)d_in[9];
    const float* bn_b = (const float*)d_in[10];
    const float* bn_m = (const float*)d_in[11];
    const float* bn_v = (const float*)d_in[12];
    float* out = (float*)d_out;

    // ws: Q | K | V bf16 (2.36 MB each) | Yp f32 [SP][B][N][C] | Mp | Sp
    char* wsp = (char*)d_ws;
    short* Qw = (short*)(wsp);
    short* Kw = (short*)(wsp + 2359296);
    short* Vw = (short*)(wsp + 4718592);
    const size_t ypOff = 7077888;
    const size_t perSplit = 4718592 + 2 * 73728;   // Yp + Mp + Sp per chunk
    int SP = 1;
    if (ws_size >= ypOff + 4 * perSplit) SP = 4;
    else if (ws_size >= ypOff + 2 * perSplit) SP = 2;
    float* Yp = (float*)(wsp + ypOff);
    float* Mp = (float*)(wsp + ypOff + (size_t)SP * 4718592);
    float* Sp = (float*)(wsp + ypOff + (size_t)SP * 4718592 + (size_t)SP * 73728);

    proj_kernel<<<NB * (NN / 64), 256, 0, stream>>>(x, g_w, g_b, th_w, th_b,
                                                    ph_w, ph_b, Qw, Kw, Vw);
    if (SP == 4) {
        attn_kernel<4><<<4 * 144, 256, 0, stream>>>(Qw, Kw, Vw, Yp, Mp, Sp);
        out_kernel<4><<<NB * (NN / 64), 256, 0, stream>>>(Yp, Mp, Sp, x, w_w, w_b,
                                                          bn_g, bn_b, bn_m, bn_v, out);
    } else if (SP == 2) {
        attn_kernel<2><<<2 * 144, 256, 0, stream>>>(Qw, Kw, Vw, Yp, Mp, Sp);
        out_kernel<2><<<NB * (NN / 64), 256, 0, stream>>>(Yp, Mp, Sp, x, w_w, w_b,
                                                          bn_g, bn_b, bn_m, bn_v, out);
    } else {
        attn_kernel<1><<<1 * 144, 256, 0, stream>>>(Qw, Kw, Vw, Yp, Mp, Sp);
        out_kernel<1><<<NB * (NN / 64), 256, 0, stream>>>(Yp, Mp, Sp, x, w_w, w_b,
                                                          bn_g, bn_b, bn_m, bn_v, out);
    }
}